// Round 1
// baseline (889.224 us; speedup 1.0000x reference)
//
#include <hip/hip_runtime.h>
#include <math.h>

#define VN 20000
#define JN 24
#define TILE 64
#define XSTRIDE 132   // 128 + 4 floats pad: float4-aligned rows, 2-way-only bank aliasing
#define EPSF 1e-8f

__device__ __forceinline__ float softplus_b(float x) {
    // softplus(100x)/100, numerically stable (matches jax.nn.softplus)
    float z = 100.0f * x;
    float sp = fmaxf(z, 0.0f) + log1pf(expf(-fabsf(z)));
    return sp * 0.01f;
}

// ---------------------------------------------------------------------------
// Kernel 1: per-joint prep. Cond-MLP (input constant over V -> 24x4 scalars)
// and blending-weight geometry folded to w = sigmoid(dot(pl,g)+h) per (j,gi).
// geom layout per (j,gi), 12 floats: g.xyz, h, Jpose.xyz, Jc.xyz, pad, pad
// ---------------------------------------------------------------------------
__global__ __launch_bounds__(384) void prep_kernel(
    const float* __restrict__ Bcond, const float* __restrict__ Bneigh,
    const float* __restrict__ ralpha, const float* __restrict__ rbeta,
    const float* __restrict__ cW0, const float* __restrict__ cb0,
    const float* __restrict__ cW1, const float* __restrict__ cb1,
    const float* __restrict__ cW2, const float* __restrict__ cb2,
    float* __restrict__ c4, float* __restrict__ geom)
{
    __shared__ float hbuf[JN][16];
    const int t = threadIdx.x;

    // --- geometry for (j, gi) ---
    if (t < JN * 2) {
        const int j = t >> 1, gi = t & 1;
        const float* nb = Bneigh + (j * 2 + gi) * 15;   // (1,J,G,5,3)
        const float tx = nb[0],  ty = nb[1],  tz = nb[2];    // Jtr_this (self)
        const float cx = nb[3],  cy = nb[4],  cz = nb[5];    // Jtr_center
        const float ox = nb[6],  oy = nb[7],  oz = nb[8];    // Jtr_other (neigh)
        const float px = nb[9],  py = nb[10], pz = nb[11];   // Jpose
        const int bid_this  = (int)nb[12];
        const int bid_other = (int)nb[13];
        // ra = elu(alpha-1)+1  ->  x>0 ? x+1 : exp(x)  with x = alpha-1
        const float xa_n = ralpha[bid_other * JN + bid_this] - 1.0f;
        const float xa_s = ralpha[bid_this * JN + bid_other] - 1.0f;
        const float a_n = xa_n > 0.0f ? xa_n + 1.0f : expf(xa_n);
        const float a_s = xa_s > 0.0f ? xa_s + 1.0f : expf(xa_s);
        const float be_n = rbeta[bid_other * JN + bid_this];
        const float be_s = rbeta[bid_this * JN + bid_other];

        const float bnx = ox - cx, bny = oy - cy, bnz = oz - cz;
        const float bsx = tx - cx, bsy = ty - cy, bsz = tz - cz;
        const float nb_n = sqrtf(bnx*bnx + bny*bny + bnz*bnz);
        const float nb_s = sqrtf(bsx*bsx + bsy*bsy + bsz*bsz);
        const float f = nb_n / (nb_n + nb_s + EPSF);
        const float vbnx = (ox - tx) * f, vbny = (oy - ty) * f, vbnz = (oz - tz) * f;
        const float g2 = -nb_s / (nb_n + EPSF);
        const float vbsx = vbnx * g2, vbsy = vbny * g2, vbsz = vbnz * g2;
        const float n_n = sqrtf(vbnx*vbnx + vbny*vbny + vbnz*vbnz);
        const float n_s = sqrtf(vbsx*vbsx + vbsy*vbsy + vbsz*vbsz);
        const float trx = ox - vbnx, tr_y = oy - vbny, trz = oz - vbnz;
        const float inn = 1.0f / ((n_n + EPSF) * (n_n + EPSF));
        const float ins = 1.0f / ((n_s + EPSF) * (n_s + EPSF));
        // e_n = vb_n/(n_n+eps)^2 ; e_s likewise; arg = dot(pl-tr_o, e_n)*a_n + be_n - dot(pl-tr_o, e_s)*a_s - be_s
        const float gx = vbnx * inn * a_n - vbsx * ins * a_s;
        const float gy = vbny * inn * a_n - vbsy * ins * a_s;
        const float gz = vbnz * inn * a_n - vbsz * ins * a_s;
        const float h = -(trx * gx + tr_y * gy + trz * gz) + be_n - be_s;
        float* gm = geom + (j * 2 + gi) * 12;
        gm[0] = gx; gm[1] = gy; gm[2] = gz; gm[3] = h;
        gm[4] = px; gm[5] = py; gm[6] = pz;
        gm[7] = cx; gm[8] = cy; gm[9] = cz;
        gm[10] = 0.0f; gm[11] = 0.0f;
    }

    // --- cond MLP: 288 -> 16 -> 16 -> 4, per joint (constant over V) ---
    {
        const int j = t >> 4, o = t & 15;   // t in [0,384): j in [0,24)
        const float* cond = Bcond + j * 288;
        const float* w = cW0 + j * 288 * 16 + o;
        float acc = cb0[j * 16 + o];
        for (int d = 0; d < 288; ++d) acc = fmaf(cond[d], w[d * 16], acc);
        hbuf[j][o] = softplus_b(acc);
    }
    __syncthreads();
    {
        const int j = t >> 4, o = t & 15;
        const float* w = cW1 + j * 256 + o;
        float acc = cb1[j * 16 + o];
        #pragma unroll
        for (int d = 0; d < 16; ++d) acc = fmaf(hbuf[j][d], w[d * 16], acc);
        acc = softplus_b(acc);
        __syncthreads();
        hbuf[j][o] = acc;
    }
    __syncthreads();
    if (t < JN * 4) {
        const int j = t >> 2, o = t & 3;
        const float* w = cW2 + j * 64 + o;
        float acc = cb2[j * 4 + o];
        #pragma unroll
        for (int d = 0; d < 16; ++d) acc = fmaf(hbuf[j][d], w[d * 4], acc);
        c4[j * 4 + o] = acc;
    }
}

// ---------------------------------------------------------------------------
// Kernel 2: main per-(joint, 64-point-tile) kernel.
// Geometry -> deformed local coords -> MLP 7->128->128->128->1 as tiled GEMM.
// Thread t: cols o0..o0+3 (o0 = (t&31)*4), points p0..p0+7 (p0 = (t>>5)*8).
// ---------------------------------------------------------------------------
__device__ __forceinline__ void layer128(float Xs[TILE][XSTRIDE],
                                         const float* __restrict__ Wj,
                                         const float* __restrict__ bj,
                                         int t, bool act)
{
    const int o0 = (t & 31) * 4, p0 = (t >> 5) * 8;
    float4 acc[8];
    const float4 bb = *(const float4*)(bj + o0);
    #pragma unroll
    for (int i = 0; i < 8; ++i) acc[i] = bb;
    for (int k0 = 0; k0 < 128; k0 += 4) {
        const float4 w0 = *(const float4*)(Wj + (k0 + 0) * 128 + o0);
        const float4 w1 = *(const float4*)(Wj + (k0 + 1) * 128 + o0);
        const float4 w2 = *(const float4*)(Wj + (k0 + 2) * 128 + o0);
        const float4 w3 = *(const float4*)(Wj + (k0 + 3) * 128 + o0);
        #pragma unroll
        for (int i = 0; i < 8; ++i) {
            const float4 xv = *(const float4*)(&Xs[p0 + i][k0]);
            acc[i].x = fmaf(xv.x, w0.x, fmaf(xv.y, w1.x, fmaf(xv.z, w2.x, fmaf(xv.w, w3.x, acc[i].x))));
            acc[i].y = fmaf(xv.x, w0.y, fmaf(xv.y, w1.y, fmaf(xv.z, w2.y, fmaf(xv.w, w3.y, acc[i].y))));
            acc[i].z = fmaf(xv.x, w0.z, fmaf(xv.y, w1.z, fmaf(xv.z, w2.z, fmaf(xv.w, w3.z, acc[i].z))));
            acc[i].w = fmaf(xv.x, w0.w, fmaf(xv.y, w1.w, fmaf(xv.z, w2.w, fmaf(xv.w, w3.w, acc[i].w))));
        }
    }
    if (act) {
        #pragma unroll
        for (int i = 0; i < 8; ++i) {
            acc[i].x = softplus_b(acc[i].x);
            acc[i].y = softplus_b(acc[i].y);
            acc[i].z = softplus_b(acc[i].z);
            acc[i].w = softplus_b(acc[i].w);
        }
    }
    __syncthreads();   // all reads of Xs done before overwrite
    #pragma unroll
    for (int i = 0; i < 8; ++i) *(float4*)(&Xs[p0 + i][o0]) = acc[i];
    __syncthreads();
}

__global__ __launch_bounds__(256) void main_kernel(
    const float* __restrict__ pts, const float* __restrict__ Btr,
    const float* __restrict__ Brot,
    const float* __restrict__ W0, const float* __restrict__ b0,
    const float* __restrict__ W1, const float* __restrict__ b1,
    const float* __restrict__ W2, const float* __restrict__ b2,
    const float* __restrict__ W3, const float* __restrict__ b3,
    const float* __restrict__ c4, const float* __restrict__ geom,
    float* __restrict__ pred)
{
    __shared__ float Xs[TILE][XSTRIDE];
    const int j = blockIdx.y;
    const int v0 = blockIdx.x * TILE;
    const int t = threadIdx.x;

    // --- phase 0: local coords + neighbor deformation, write 7-dim input ---
    if (t < TILE) {
        const int v = v0 + t;
        float plx = 0.0f, ply = 0.0f, plz = 0.0f;
        if (v < VN) {
            const float dx = pts[v * 3 + 0] - Btr[j * 3 + 0];
            const float dy = pts[v * 3 + 1] - Btr[j * 3 + 1];
            const float dz = pts[v * 3 + 2] - Btr[j * 3 + 2];
            const float* R = Brot + j * 9;
            plx = R[0] * dx + R[3] * dy + R[6] * dz;   // Brot^T
            ply = R[1] * dx + R[4] * dy + R[7] * dz;
            plz = R[2] * dx + R[5] * dy + R[8] * dz;
            float osx = 0.0f, osy = 0.0f, osz = 0.0f;
            #pragma unroll
            for (int gi = 0; gi < 2; ++gi) {
                const float* gm = geom + (j * 2 + gi) * 12;
                const float arg = plx * gm[0] + ply * gm[1] + plz * gm[2] + gm[3];
                const float w = 1.0f / (1.0f + expf(-arg));
                const float aax = -gm[4] * w, aay = -gm[5] * w, aaz = -gm[6] * w;
                const float jcx = gm[7], jcy = gm[8], jcz = gm[9];
                const float ang = sqrtf(aax * aax + aay * aay + aaz * aaz);
                const float inv = ang < 1e-12f ? 1.0f : 1.0f / ang;
                const float ux = aax * inv, uy = aay * inv, uz = aaz * inv;
                const float co = cosf(ang), si = sinf(ang), C = 1.0f - co;
                const float vx = plx - jcx, vy = ply - jcy, vz = plz - jcz;
                const float du = ux * vx + uy * vy + uz * vz;
                const float cxv = uy * vz - uz * vy;
                const float cyv = uz * vx - ux * vz;
                const float czv = ux * vy - uy * vx;
                // R v = c v + s (u x v) + C u (u.v);  off = Rv + Jc - pl
                float offx = co * vx + si * cxv + C * ux * du + jcx - plx;
                float offy = co * vy + si * cyv + C * uy * du + jcy - ply;
                float offz = co * vz + si * czv + C * uz * du + jcz - plz;
                if (isnan(offx)) offx = 0.0f;   // nan_to_num
                if (isnan(offy)) offy = 0.0f;
                if (isnan(offz)) offz = 0.0f;
                osx += offx; osy += offy; osz += offz;
            }
            plx += osx; ply += osy; plz += osz;
        }
        Xs[t][0] = plx; Xs[t][1] = ply; Xs[t][2] = plz;
        Xs[t][3] = c4[j * 4 + 0];
        Xs[t][4] = c4[j * 4 + 1];
        Xs[t][5] = c4[j * 4 + 2];
        Xs[t][6] = c4[j * 4 + 3];
    }
    __syncthreads();

    // --- layer 0: 7 -> 128 ---
    {
        const int o0 = (t & 31) * 4, p0 = (t >> 5) * 8;
        const float* Wj = W0 + j * 7 * 128;
        const float* bj = b0 + j * 128;
        float4 acc[8];
        const float4 bb = *(const float4*)(bj + o0);
        #pragma unroll
        for (int i = 0; i < 8; ++i) acc[i] = bb;
        #pragma unroll
        for (int kk = 0; kk < 7; ++kk) {
            const float4 w = *(const float4*)(Wj + kk * 128 + o0);
            #pragma unroll
            for (int i = 0; i < 8; ++i) {
                const float xv = Xs[p0 + i][kk];
                acc[i].x = fmaf(xv, w.x, acc[i].x);
                acc[i].y = fmaf(xv, w.y, acc[i].y);
                acc[i].z = fmaf(xv, w.z, acc[i].z);
                acc[i].w = fmaf(xv, w.w, acc[i].w);
            }
        }
        #pragma unroll
        for (int i = 0; i < 8; ++i) {
            acc[i].x = softplus_b(acc[i].x);
            acc[i].y = softplus_b(acc[i].y);
            acc[i].z = softplus_b(acc[i].z);
            acc[i].w = softplus_b(acc[i].w);
        }
        __syncthreads();
        #pragma unroll
        for (int i = 0; i < 8; ++i) *(float4*)(&Xs[p0 + i][o0]) = acc[i];
        __syncthreads();
    }

    // --- layers 1,2: 128 -> 128 ---
    layer128(Xs, W1 + j * 128 * 128, b1 + j * 128, t, true);
    layer128(Xs, W2 + j * 128 * 128, b2 + j * 128, t, true);

    // --- layer 3: 128 -> 1 ---
    if (t < TILE) {
        const int v = v0 + t;
        const float* w3 = W3 + j * 128;
        float acc = b3[j];
        for (int k0 = 0; k0 < 128; k0 += 4) {
            const float4 xv = *(const float4*)(&Xs[t][k0]);
            const float4 wv = *(const float4*)(w3 + k0);
            acc = fmaf(xv.x, wv.x, fmaf(xv.y, wv.y, fmaf(xv.z, wv.z, fmaf(xv.w, wv.w, acc))));
        }
        if (v < VN) pred[j * VN + v] = acc;
    }
}

// ---------------------------------------------------------------------------
// Kernel 3: softmin blend over J
// ---------------------------------------------------------------------------
__global__ __launch_bounds__(256) void softmin_kernel(const float* __restrict__ pred,
                                                      float* __restrict__ out)
{
    const int v = blockIdx.x * 256 + threadIdx.x;
    if (v >= VN) return;
    float vals[JN];
    float m = 3.4e38f;
    #pragma unroll
    for (int jj = 0; jj < JN; ++jj) {
        vals[jj] = pred[jj * VN + v];
        m = fminf(m, vals[jj]);
    }
    float s1 = 0.0f, s2 = 0.0f;
    #pragma unroll
    for (int jj = 0; jj < JN; ++jj) {
        const float d = vals[jj] - m;
        const float e = expf(-200.0f * d);
        s1 += e;
        s2 = fmaf(d, e, s2);
    }
    out[v] = s2 / s1 + m;
}

extern "C" void kernel_launch(void* const* d_in, const int* in_sizes, int n_in,
                              void* d_out, int out_size, void* d_ws, size_t ws_size,
                              hipStream_t stream)
{
    const float* pts    = (const float*)d_in[0];
    const float* Bcond  = (const float*)d_in[1];
    const float* Btr    = (const float*)d_in[2];
    const float* Brot   = (const float*)d_in[3];
    const float* Bneigh = (const float*)d_in[4];
    const float* ralpha = (const float*)d_in[5];
    const float* rbeta  = (const float*)d_in[6];
    const float* cW0 = (const float*)d_in[7];
    const float* cb0 = (const float*)d_in[8];
    const float* cW1 = (const float*)d_in[9];
    const float* cb1 = (const float*)d_in[10];
    const float* cW2 = (const float*)d_in[11];
    const float* cb2 = (const float*)d_in[12];
    const float* W0 = (const float*)d_in[13];
    const float* b0 = (const float*)d_in[14];
    const float* W1 = (const float*)d_in[15];
    const float* b1 = (const float*)d_in[16];
    const float* W2 = (const float*)d_in[17];
    const float* b2 = (const float*)d_in[18];
    const float* W3 = (const float*)d_in[19];
    const float* b3 = (const float*)d_in[20];

    float* ws   = (float*)d_ws;
    float* pred = ws;                       // JN*VN floats
    float* c4   = ws + JN * VN;             // JN*4
    float* geom = c4 + JN * 4;              // JN*2*12

    prep_kernel<<<1, 384, 0, stream>>>(Bcond, Bneigh, ralpha, rbeta,
                                       cW0, cb0, cW1, cb1, cW2, cb2, c4, geom);

    dim3 grid((VN + TILE - 1) / TILE, JN);
    main_kernel<<<grid, 256, 0, stream>>>(pts, Btr, Brot,
                                          W0, b0, W1, b1, W2, b2, W3, b3,
                                          c4, geom, pred);

    softmin_kernel<<<(VN + 255) / 256, 256, 0, stream>>>(pred, (float*)d_out);
}

// Round 2
// 561.221 us; speedup vs baseline: 1.5844x; 1.5844x over previous
//
#include <hip/hip_runtime.h>
#include <math.h>

#define VN 20000
#define JN 24
#define TILE 64          // points per block
#define ROWS 132         // LDS rows: 128 activations + 4 stash
#define EPSF 1e-8f

__device__ __forceinline__ float softplus_fast(float x) {
    // softplus(100x)/100 via native exp/log; error ~1e-7 absolute after *0.01
    const float z = 100.0f * x;
    const float e = __expf(-fabsf(z));
    const float l = __logf(1.0f + e);
    return (fmaxf(z, 0.0f) + l) * 0.01f;
}

// ---------------------------------------------------------------------------
// Kernel 1: per-joint prep. Cond-MLP (input constant over V -> 24x4 scalars)
// and blending-weight geometry folded to w = sigmoid(dot(pl,g)+h) per (j,gi).
// geom layout per (j,gi), 12 floats: g.xyz, h, Jpose.xyz, Jc.xyz, pad, pad
// ---------------------------------------------------------------------------
__global__ __launch_bounds__(384) void prep_kernel(
    const float* __restrict__ Bcond, const float* __restrict__ Bneigh,
    const float* __restrict__ ralpha, const float* __restrict__ rbeta,
    const float* __restrict__ cW0, const float* __restrict__ cb0,
    const float* __restrict__ cW1, const float* __restrict__ cb1,
    const float* __restrict__ cW2, const float* __restrict__ cb2,
    float* __restrict__ c4, float* __restrict__ geom)
{
    __shared__ float hbuf[JN][16];
    const int t = threadIdx.x;

    // --- geometry for (j, gi) ---
    if (t < JN * 2) {
        const int j = t >> 1, gi = t & 1;
        const float* nb = Bneigh + (j * 2 + gi) * 15;   // (1,J,G,5,3)
        const float tx = nb[0],  ty = nb[1],  tz = nb[2];    // Jtr_this (self)
        const float cx = nb[3],  cy = nb[4],  cz = nb[5];    // Jtr_center
        const float ox = nb[6],  oy = nb[7],  oz = nb[8];    // Jtr_other (neigh)
        const float px = nb[9],  py = nb[10], pz = nb[11];   // Jpose
        const int bid_this  = (int)nb[12];
        const int bid_other = (int)nb[13];
        const float xa_n = ralpha[bid_other * JN + bid_this] - 1.0f;
        const float xa_s = ralpha[bid_this * JN + bid_other] - 1.0f;
        const float a_n = xa_n > 0.0f ? xa_n + 1.0f : expf(xa_n);
        const float a_s = xa_s > 0.0f ? xa_s + 1.0f : expf(xa_s);
        const float be_n = rbeta[bid_other * JN + bid_this];
        const float be_s = rbeta[bid_this * JN + bid_other];

        const float bnx = ox - cx, bny = oy - cy, bnz = oz - cz;
        const float bsx = tx - cx, bsy = ty - cy, bsz = tz - cz;
        const float nb_n = sqrtf(bnx*bnx + bny*bny + bnz*bnz);
        const float nb_s = sqrtf(bsx*bsx + bsy*bsy + bsz*bsz);
        const float f = nb_n / (nb_n + nb_s + EPSF);
        const float vbnx = (ox - tx) * f, vbny = (oy - ty) * f, vbnz = (oz - tz) * f;
        const float g2 = -nb_s / (nb_n + EPSF);
        const float vbsx = vbnx * g2, vbsy = vbny * g2, vbsz = vbnz * g2;
        const float n_n = sqrtf(vbnx*vbnx + vbny*vbny + vbnz*vbnz);
        const float n_s = sqrtf(vbsx*vbsx + vbsy*vbsy + vbsz*vbsz);
        const float trx = ox - vbnx, tr_y = oy - vbny, trz = oz - vbnz;
        const float inn = 1.0f / ((n_n + EPSF) * (n_n + EPSF));
        const float ins = 1.0f / ((n_s + EPSF) * (n_s + EPSF));
        const float gx = vbnx * inn * a_n - vbsx * ins * a_s;
        const float gy = vbny * inn * a_n - vbsy * ins * a_s;
        const float gz = vbnz * inn * a_n - vbsz * ins * a_s;
        const float h = -(trx * gx + tr_y * gy + trz * gz) + be_n - be_s;
        float* gm = geom + (j * 2 + gi) * 12;
        gm[0] = gx; gm[1] = gy; gm[2] = gz; gm[3] = h;
        gm[4] = px; gm[5] = py; gm[6] = pz;
        gm[7] = cx; gm[8] = cy; gm[9] = cz;
        gm[10] = 0.0f; gm[11] = 0.0f;
    }

    // --- cond MLP: 288 -> 16 -> 16 -> 4, per joint (constant over V) ---
    {
        const int j = t >> 4, o = t & 15;   // t in [0,384): j in [0,24)
        const float* cond = Bcond + j * 288;
        const float* w = cW0 + j * 288 * 16 + o;
        float acc = cb0[j * 16 + o];
        for (int d = 0; d < 288; ++d) acc = fmaf(cond[d], w[d * 16], acc);
        hbuf[j][o] = softplus_fast(acc);
    }
    __syncthreads();
    {
        const int j = t >> 4, o = t & 15;
        const float* w = cW1 + j * 256 + o;
        float acc = cb1[j * 16 + o];
        #pragma unroll
        for (int d = 0; d < 16; ++d) acc = fmaf(hbuf[j][d], w[d * 16], acc);
        acc = softplus_fast(acc);
        __syncthreads();
        hbuf[j][o] = acc;
    }
    __syncthreads();
    if (t < JN * 4) {
        const int j = t >> 2, o = t & 3;
        const float* w = cW2 + j * 64 + o;
        float acc = cb2[j * 4 + o];
        #pragma unroll
        for (int d = 0; d < 16; ++d) acc = fmaf(hbuf[j][d], w[d * 4], acc);
        c4[j * 4 + o] = acc;
    }
}

// ---------------------------------------------------------------------------
// Kernel 2: main per-(joint, 64-point-tile) kernel.
// Activations transposed in LDS: Xs[k][p] (row stride 64 -> conflict-free).
// Thread t: point p = t&63, output-quarter q = readfirstlane(t>>6).
// Weights are wave-uniform -> s_load into SGPRs, inner loop pure v_fmac.
// ---------------------------------------------------------------------------
__device__ __forceinline__ void mlp_layer(float* __restrict__ Xs,
                                          const float* __restrict__ Wj,   // [kdim][128] row-major, wave-uniform
                                          const float* __restrict__ bj,   // [128], wave-uniform
                                          int p, int q, int kdim, bool act)
{
    float acc[32];
    {
        const float4* b4 = (const float4*)(bj + q * 32);   // uniform -> s_load
        #pragma unroll
        for (int i = 0; i < 8; ++i) {
            const float4 b = b4[i];
            acc[4*i+0] = b.x; acc[4*i+1] = b.y; acc[4*i+2] = b.z; acc[4*i+3] = b.w;
        }
    }
    const float* wbase = Wj + q * 32;                      // uniform
    #pragma unroll 4
    for (int k = 0; k < kdim; ++k) {
        const float xk = Xs[k * TILE + p];                 // ds_read_b32, stride-1 lanes
        const float* wr = wbase + k * 128;                 // uniform row -> s_load_dwordx16
        #pragma unroll
        for (int oo = 0; oo < 32; ++oo)
            acc[oo] = fmaf(xk, wr[oo], acc[oo]);           // v_fmac vdst, sgpr, vgpr
    }
    __syncthreads();                                       // all reads done before overwrite
    #pragma unroll
    for (int oo = 0; oo < 32; ++oo) {
        const float v = act ? softplus_fast(acc[oo]) : acc[oo];
        Xs[(q * 32 + oo) * TILE + p] = v;
    }
    __syncthreads();
}

__global__ __launch_bounds__(256) void main_kernel(
    const float* __restrict__ pts, const float* __restrict__ Btr,
    const float* __restrict__ Brot,
    const float* __restrict__ W0, const float* __restrict__ b0,
    const float* __restrict__ W1, const float* __restrict__ b1,
    const float* __restrict__ W2, const float* __restrict__ b2,
    const float* __restrict__ W3, const float* __restrict__ b3,
    const float* __restrict__ c4, const float* __restrict__ geom,
    float* __restrict__ pred)
{
    __shared__ float Xs[ROWS * TILE];
    const int j = blockIdx.y;
    const int v0 = blockIdx.x * TILE;
    const int t = threadIdx.x;
    const int p = t & 63;
    const int q = __builtin_amdgcn_readfirstlane(t >> 6);  // wave-uniform output quarter

    // --- phase 0: local coords + neighbor deformation -> 7-dim input rows ---
    if (t < TILE) {
        const int v = v0 + t;
        float plx = 0.0f, ply = 0.0f, plz = 0.0f;
        if (v < VN) {
            const float dx = pts[v * 3 + 0] - Btr[j * 3 + 0];
            const float dy = pts[v * 3 + 1] - Btr[j * 3 + 1];
            const float dz = pts[v * 3 + 2] - Btr[j * 3 + 2];
            const float* R = Brot + j * 9;
            plx = R[0] * dx + R[3] * dy + R[6] * dz;   // Brot^T
            ply = R[1] * dx + R[4] * dy + R[7] * dz;
            plz = R[2] * dx + R[5] * dy + R[8] * dz;
            float osx = 0.0f, osy = 0.0f, osz = 0.0f;
            #pragma unroll
            for (int gi = 0; gi < 2; ++gi) {
                const float* gm = geom + (j * 2 + gi) * 12;
                const float arg = plx * gm[0] + ply * gm[1] + plz * gm[2] + gm[3];
                const float w = 1.0f / (1.0f + __expf(-arg));
                const float aax = -gm[4] * w, aay = -gm[5] * w, aaz = -gm[6] * w;
                const float jcx = gm[7], jcy = gm[8], jcz = gm[9];
                const float ang = sqrtf(aax * aax + aay * aay + aaz * aaz);
                const float inv = ang < 1e-12f ? 1.0f : 1.0f / ang;
                const float ux = aax * inv, uy = aay * inv, uz = aaz * inv;
                const float co = __cosf(ang), si = __sinf(ang), C = 1.0f - co;
                const float vx = plx - jcx, vy = ply - jcy, vz = plz - jcz;
                const float du = ux * vx + uy * vy + uz * vz;
                const float cxv = uy * vz - uz * vy;
                const float cyv = uz * vx - ux * vz;
                const float czv = ux * vy - uy * vx;
                float offx = co * vx + si * cxv + C * ux * du + jcx - plx;
                float offy = co * vy + si * cyv + C * uy * du + jcy - ply;
                float offz = co * vz + si * czv + C * uz * du + jcz - plz;
                if (isnan(offx)) offx = 0.0f;   // nan_to_num
                if (isnan(offy)) offy = 0.0f;
                if (isnan(offz)) offz = 0.0f;
                osx += offx; osy += offy; osz += offz;
            }
            plx += osx; ply += osy; plz += osz;
        }
        Xs[0 * TILE + t] = plx;
        Xs[1 * TILE + t] = ply;
        Xs[2 * TILE + t] = plz;
        Xs[3 * TILE + t] = c4[j * 4 + 0];   // uniform -> s_load broadcast
        Xs[4 * TILE + t] = c4[j * 4 + 1];
        Xs[5 * TILE + t] = c4[j * 4 + 2];
        Xs[6 * TILE + t] = c4[j * 4 + 3];
    }
    __syncthreads();

    // --- MLP 7 -> 128 -> 128 -> 128 ---
    mlp_layer(Xs, W0 + j * 7   * 128, b0 + j * 128, p, q, 7,   true);
    mlp_layer(Xs, W1 + j * 128 * 128, b1 + j * 128, p, q, 128, true);
    mlp_layer(Xs, W2 + j * 128 * 128, b2 + j * 128, p, q, 128, true);

    // --- layer 3: 128 -> 1, split over q, reduce via stash rows 128..131 ---
    {
        const float* w3 = W3 + j * 128 + q * 32;           // uniform
        float part = 0.0f;
        #pragma unroll 4
        for (int kk = 0; kk < 32; ++kk)
            part = fmaf(Xs[(q * 32 + kk) * TILE + p], w3[kk], part);
        Xs[(128 + q) * TILE + p] = part;                   // rows 0..127 untouched: no pre-barrier
    }
    __syncthreads();
    if (t < TILE) {
        const int v = v0 + t;
        const float r = b3[j] + Xs[128 * TILE + t] + Xs[129 * TILE + t]
                              + Xs[130 * TILE + t] + Xs[131 * TILE + t];
        if (v < VN) pred[j * VN + v] = r;
    }
}

// ---------------------------------------------------------------------------
// Kernel 3: softmin blend over J
// ---------------------------------------------------------------------------
__global__ __launch_bounds__(256) void softmin_kernel(const float* __restrict__ pred,
                                                      float* __restrict__ out)
{
    const int v = blockIdx.x * 256 + threadIdx.x;
    if (v >= VN) return;
    float vals[JN];
    float m = 3.4e38f;
    #pragma unroll
    for (int jj = 0; jj < JN; ++jj) {
        vals[jj] = pred[jj * VN + v];
        m = fminf(m, vals[jj]);
    }
    float s1 = 0.0f, s2 = 0.0f;
    #pragma unroll
    for (int jj = 0; jj < JN; ++jj) {
        const float d = vals[jj] - m;
        const float e = __expf(-200.0f * d);
        s1 += e;
        s2 = fmaf(d, e, s2);
    }
    out[v] = s2 / s1 + m;
}

extern "C" void kernel_launch(void* const* d_in, const int* in_sizes, int n_in,
                              void* d_out, int out_size, void* d_ws, size_t ws_size,
                              hipStream_t stream)
{
    const float* pts    = (const float*)d_in[0];
    const float* Bcond  = (const float*)d_in[1];
    const float* Btr    = (const float*)d_in[2];
    const float* Brot   = (const float*)d_in[3];
    const float* Bneigh = (const float*)d_in[4];
    const float* ralpha = (const float*)d_in[5];
    const float* rbeta  = (const float*)d_in[6];
    const float* cW0 = (const float*)d_in[7];
    const float* cb0 = (const float*)d_in[8];
    const float* cW1 = (const float*)d_in[9];
    const float* cb1 = (const float*)d_in[10];
    const float* cW2 = (const float*)d_in[11];
    const float* cb2 = (const float*)d_in[12];
    const float* W0 = (const float*)d_in[13];
    const float* b0 = (const float*)d_in[14];
    const float* W1 = (const float*)d_in[15];
    const float* b1 = (const float*)d_in[16];
    const float* W2 = (const float*)d_in[17];
    const float* b2 = (const float*)d_in[18];
    const float* W3 = (const float*)d_in[19];
    const float* b3 = (const float*)d_in[20];

    float* ws   = (float*)d_ws;
    float* pred = ws;                       // JN*VN floats
    float* c4   = ws + JN * VN;             // JN*4
    float* geom = c4 + JN * 4;              // JN*2*12

    prep_kernel<<<1, 384, 0, stream>>>(Bcond, Bneigh, ralpha, rbeta,
                                       cW0, cb0, cW1, cb1, cW2, cb2, c4, geom);

    dim3 grid((VN + TILE - 1) / TILE, JN);
    main_kernel<<<grid, 256, 0, stream>>>(pts, Btr, Brot,
                                          W0, b0, W1, b1, W2, b2, W3, b3,
                                          c4, geom, pred);

    softmin_kernel<<<(VN + 255) / 256, 256, 0, stream>>>(pred, (float*)d_out);
}

// Round 3
// 304.261 us; speedup vs baseline: 2.9226x; 1.8445x over previous
//
#include <hip/hip_runtime.h>
#include <hip/hip_bf16.h>
#include <math.h>

#define VN 20000
#define JN 24
#define TILE 64
#define KP 132            // packed-activation row pitch in dwords (132%32=4 -> 2-way max)
#define EPSF 1e-8f

typedef __attribute__((ext_vector_type(8))) short bfrag;   // 8 bf16 = 4 VGPRs
typedef __attribute__((ext_vector_type(4))) float f32x4;

// per-joint bf16 weight-plane offsets (ushort units)
#define WJ_STRIDE 73728
#define L0H 0
#define L0L 4096
#define L1H 8192
#define L1L 24576
#define L2H 40960
#define L2L 57344

__device__ __forceinline__ unsigned short f2bf(float x) {
    __hip_bfloat16 b = __float2bfloat16(x);
    unsigned short u; __builtin_memcpy(&u, &b, 2); return u;
}
__device__ __forceinline__ float bf2f(unsigned short u) {
    __hip_bfloat16 b; __builtin_memcpy(&b, &u, 2);
    return __bfloat162float(b);
}
__device__ __forceinline__ unsigned int pack_hl(float x) {
    const unsigned short h = f2bf(x);
    const unsigned short l = f2bf(x - bf2f(h));
    return (unsigned int)h | ((unsigned int)l << 16);
}

__device__ __forceinline__ float softplus_fast(float x) {
    const float z = 100.0f * x;
    const float e = __expf(-fabsf(z));
    const float l = __logf(1.0f + e);
    return (fmaxf(z, 0.0f) + l) * 0.01f;
}

// ---------------------------------------------------------------------------
// Kernel 1: per-joint prep (cond-MLP 288->16->16->4 + blending geometry fold)
// geom per (j,gi), 12 floats: g.xyz, h, Jpose.xyz, Jc.xyz, pad, pad
// ---------------------------------------------------------------------------
__global__ __launch_bounds__(384) void prep_kernel(
    const float* __restrict__ Bcond, const float* __restrict__ Bneigh,
    const float* __restrict__ ralpha, const float* __restrict__ rbeta,
    const float* __restrict__ cW0, const float* __restrict__ cb0,
    const float* __restrict__ cW1, const float* __restrict__ cb1,
    const float* __restrict__ cW2, const float* __restrict__ cb2,
    float* __restrict__ c4, float* __restrict__ geom)
{
    __shared__ float hbuf[JN][16];
    const int t = threadIdx.x;

    if (t < JN * 2) {
        const int j = t >> 1, gi = t & 1;
        const float* nb = Bneigh + (j * 2 + gi) * 15;
        const float tx = nb[0],  ty = nb[1],  tz = nb[2];
        const float cx = nb[3],  cy = nb[4],  cz = nb[5];
        const float ox = nb[6],  oy = nb[7],  oz = nb[8];
        const float px = nb[9],  py = nb[10], pz = nb[11];
        const int bid_this  = (int)nb[12];
        const int bid_other = (int)nb[13];
        const float xa_n = ralpha[bid_other * JN + bid_this] - 1.0f;
        const float xa_s = ralpha[bid_this * JN + bid_other] - 1.0f;
        const float a_n = xa_n > 0.0f ? xa_n + 1.0f : expf(xa_n);
        const float a_s = xa_s > 0.0f ? xa_s + 1.0f : expf(xa_s);
        const float be_n = rbeta[bid_other * JN + bid_this];
        const float be_s = rbeta[bid_this * JN + bid_other];

        const float bnx = ox - cx, bny = oy - cy, bnz = oz - cz;
        const float bsx = tx - cx, bsy = ty - cy, bsz = tz - cz;
        const float nb_n = sqrtf(bnx*bnx + bny*bny + bnz*bnz);
        const float nb_s = sqrtf(bsx*bsx + bsy*bsy + bsz*bsz);
        const float f = nb_n / (nb_n + nb_s + EPSF);
        const float vbnx = (ox - tx) * f, vbny = (oy - ty) * f, vbnz = (oz - tz) * f;
        const float g2 = -nb_s / (nb_n + EPSF);
        const float vbsx = vbnx * g2, vbsy = vbny * g2, vbsz = vbnz * g2;
        const float n_n = sqrtf(vbnx*vbnx + vbny*vbny + vbnz*vbnz);
        const float n_s = sqrtf(vbsx*vbsx + vbsy*vbsy + vbsz*vbsz);
        const float trx = ox - vbnx, tr_y = oy - vbny, trz = oz - vbnz;
        const float inn = 1.0f / ((n_n + EPSF) * (n_n + EPSF));
        const float ins = 1.0f / ((n_s + EPSF) * (n_s + EPSF));
        const float gx = vbnx * inn * a_n - vbsx * ins * a_s;
        const float gy = vbny * inn * a_n - vbsy * ins * a_s;
        const float gz = vbnz * inn * a_n - vbsz * ins * a_s;
        const float h = -(trx * gx + tr_y * gy + trz * gz) + be_n - be_s;
        float* gm = geom + (j * 2 + gi) * 12;
        gm[0] = gx; gm[1] = gy; gm[2] = gz; gm[3] = h;
        gm[4] = px; gm[5] = py; gm[6] = pz;
        gm[7] = cx; gm[8] = cy; gm[9] = cz;
        gm[10] = 0.0f; gm[11] = 0.0f;
    }

    {
        const int j = t >> 4, o = t & 15;
        const float* cond = Bcond + j * 288;
        const float* w = cW0 + j * 288 * 16 + o;
        float acc = cb0[j * 16 + o];
        for (int d = 0; d < 288; ++d) acc = fmaf(cond[d], w[d * 16], acc);
        hbuf[j][o] = softplus_fast(acc);
    }
    __syncthreads();
    {
        const int j = t >> 4, o = t & 15;
        const float* w = cW1 + j * 256 + o;
        float acc = cb1[j * 16 + o];
        #pragma unroll
        for (int d = 0; d < 16; ++d) acc = fmaf(hbuf[j][d], w[d * 16], acc);
        acc = softplus_fast(acc);
        __syncthreads();
        hbuf[j][o] = acc;
    }
    __syncthreads();
    if (t < JN * 4) {
        const int j = t >> 2, o = t & 3;
        const float* w = cW2 + j * 64 + o;
        float acc = cb2[j * 4 + o];
        #pragma unroll
        for (int d = 0; d < 16; ++d) acc = fmaf(hbuf[j][d], w[d * 4], acc);
        c4[j * 4 + o] = acc;
    }
}

// ---------------------------------------------------------------------------
// Kernel 2: weight split/transpose into B-fragment order, bf16 hi/lo planes.
// Storage idx within a layer plane: ((ks*8 + ntile)*64 + lane)*8 + j8
// maps to W[k][n] with n = ntile*16 + (lane&15), k = ks*32 + (lane>>4)*8 + j8
// ---------------------------------------------------------------------------
__global__ __launch_bounds__(256) void wprep_kernel(
    const float* __restrict__ W0, const float* __restrict__ W1,
    const float* __restrict__ W2, unsigned short* __restrict__ wt)
{
    const int g = blockIdx.x * 256 + threadIdx.x;   // < 24*36864
    const int jj = g / 36864;
    const int r = g - jj * 36864;
    const float* src; int idx, kin, hoff, loff;
    if (r < 4096)       { idx = r;         kin = 7;   src = W0 + jj * 896;   hoff = L0H; loff = L0L; }
    else if (r < 20480) { idx = r - 4096;  kin = 128; src = W1 + jj * 16384; hoff = L1H; loff = L1L; }
    else                { idx = r - 20480; kin = 128; src = W2 + jj * 16384; hoff = L2H; loff = L2L; }
    const int j8   = idx & 7;
    const int lane = (idx >> 3) & 63;
    const int nt   = (idx >> 9) & 7;
    const int ks   = idx >> 12;
    const int n = nt * 16 + (lane & 15);
    const int k = ks * 32 + (lane >> 4) * 8 + j8;
    const float v = (k < kin) ? src[k * 128 + n] : 0.0f;
    const unsigned short h = f2bf(v);
    const unsigned short l = f2bf(v - bf2f(h));
    unsigned short* dj = wt + jj * WJ_STRIDE;
    dj[hoff + idx] = h;
    dj[loff + idx] = l;
}

// ---------------------------------------------------------------------------
// Kernel 3: main. 64 points x 1 joint per block; MLP on matrix cores with
// split-bf16 compensation (Whi*xhi + Whi*xlo + Wlo*xhi, fp32 accumulate).
// Activations in LDS as (hi | lo<<16) dwords, [p][k] pitch 132.
// Wave q owns output cols [q*32, q*32+32).
// ---------------------------------------------------------------------------
__device__ __forceinline__ void mfma_layer(
    unsigned int* __restrict__ X,
    const unsigned short* __restrict__ wh,
    const unsigned short* __restrict__ wl,
    const float* __restrict__ bvec,
    int q, int lane, int nks)
{
    const int l = lane & 15;
    const int quad = lane >> 4;
    const f32x4 fz = {0.0f, 0.0f, 0.0f, 0.0f};
    f32x4 acc[4][2];
    #pragma unroll
    for (int mi = 0; mi < 4; ++mi)
        #pragma unroll
        for (int ni = 0; ni < 2; ++ni)
            acc[mi][ni] = fz;

    #pragma unroll 1
    for (int ks = 0; ks < nks; ++ks) {
        bfrag bh[2], bl[2];
        #pragma unroll
        for (int ni = 0; ni < 2; ++ni) {
            const int off = ((ks * 8 + (q * 2 + ni)) * 64 + lane) * 8;
            bh[ni] = *(const bfrag*)(wh + off);   // coalesced 16B/lane
            bl[ni] = *(const bfrag*)(wl + off);
        }
        #pragma unroll
        for (int mi = 0; mi < 4; ++mi) {
            const unsigned int* ap = X + (mi * 16 + l) * KP + ks * 32 + quad * 8;
            union { uint4 v[2]; unsigned int u[8]; } d;
            d.v[0] = *(const uint4*)ap;           // ds_read_b128 x2
            d.v[1] = *(const uint4*)(ap + 4);
            union { unsigned short s[8]; bfrag f; } ah, al;
            #pragma unroll
            for (int jj = 0; jj < 8; ++jj) {
                ah.s[jj] = (unsigned short)(d.u[jj] & 0xffffu);
                al.s[jj] = (unsigned short)(d.u[jj] >> 16);
            }
            #pragma unroll
            for (int ni = 0; ni < 2; ++ni) {
                acc[mi][ni] = __builtin_amdgcn_mfma_f32_16x16x32_bf16(ah.f, bh[ni], acc[mi][ni], 0, 0, 0);
                acc[mi][ni] = __builtin_amdgcn_mfma_f32_16x16x32_bf16(ah.f, bl[ni], acc[mi][ni], 0, 0, 0);
                acc[mi][ni] = __builtin_amdgcn_mfma_f32_16x16x32_bf16(al.f, bh[ni], acc[mi][ni], 0, 0, 0);
            }
        }
    }
    __syncthreads();   // all A reads done before overwrite
    #pragma unroll
    for (int ni = 0; ni < 2; ++ni) {
        const float bia = bvec[q * 32 + ni * 16 + l];
        #pragma unroll
        for (int mi = 0; mi < 4; ++mi) {
            #pragma unroll
            for (int r = 0; r < 4; ++r) {
                float v = acc[mi][ni][r] + bia;
                v = softplus_fast(v);
                X[(mi * 16 + quad * 4 + r) * KP + (q * 32 + ni * 16 + l)] = pack_hl(v);
            }
        }
    }
    __syncthreads();
}

__global__ __launch_bounds__(256, 4) void main_kernel(
    const float* __restrict__ pts, const float* __restrict__ Btr,
    const float* __restrict__ Brot,
    const float* __restrict__ b0, const float* __restrict__ b1,
    const float* __restrict__ b2, const float* __restrict__ W3,
    const float* __restrict__ b3,
    const float* __restrict__ c4, const float* __restrict__ geom,
    const unsigned short* __restrict__ wt,
    float* __restrict__ pred)
{
    __shared__ unsigned int X[TILE * KP];
    const int j = blockIdx.y;
    const int v0 = blockIdx.x * TILE;
    const int t = threadIdx.x;
    const int lane = t & 63;
    const int q = __builtin_amdgcn_readfirstlane(t >> 6);

    // --- phase 0: local coords + neighbor deformation -> packed input rows ---
    if (t < TILE) {
        const int v = v0 + t;
        float plx = 0.0f, ply = 0.0f, plz = 0.0f;
        if (v < VN) {
            const float dx = pts[v * 3 + 0] - Btr[j * 3 + 0];
            const float dy = pts[v * 3 + 1] - Btr[j * 3 + 1];
            const float dz = pts[v * 3 + 2] - Btr[j * 3 + 2];
            const float* R = Brot + j * 9;
            plx = R[0] * dx + R[3] * dy + R[6] * dz;
            ply = R[1] * dx + R[4] * dy + R[7] * dz;
            plz = R[2] * dx + R[5] * dy + R[8] * dz;
            float osx = 0.0f, osy = 0.0f, osz = 0.0f;
            #pragma unroll
            for (int gi = 0; gi < 2; ++gi) {
                const float* gm = geom + (j * 2 + gi) * 12;
                const float arg = plx * gm[0] + ply * gm[1] + plz * gm[2] + gm[3];
                const float w = 1.0f / (1.0f + __expf(-arg));
                const float aax = -gm[4] * w, aay = -gm[5] * w, aaz = -gm[6] * w;
                const float jcx = gm[7], jcy = gm[8], jcz = gm[9];
                const float ang = sqrtf(aax * aax + aay * aay + aaz * aaz);
                const float inv = ang < 1e-12f ? 1.0f : 1.0f / ang;
                const float ux = aax * inv, uy = aay * inv, uz = aaz * inv;
                const float co = __cosf(ang), si = __sinf(ang), C = 1.0f - co;
                const float vx = plx - jcx, vy = ply - jcy, vz = plz - jcz;
                const float du = ux * vx + uy * vy + uz * vz;
                const float cxv = uy * vz - uz * vy;
                const float cyv = uz * vx - ux * vz;
                const float czv = ux * vy - uy * vx;
                float offx = co * vx + si * cxv + C * ux * du + jcx - plx;
                float offy = co * vy + si * cyv + C * uy * du + jcy - ply;
                float offz = co * vz + si * czv + C * uz * du + jcz - plz;
                if (isnan(offx)) offx = 0.0f;
                if (isnan(offy)) offy = 0.0f;
                if (isnan(offz)) offz = 0.0f;
                osx += offx; osy += offy; osz += offz;
            }
            plx += osx; ply += osy; plz += osz;
        }
        X[t * KP + 0] = pack_hl(plx);
        X[t * KP + 1] = pack_hl(ply);
        X[t * KP + 2] = pack_hl(plz);
        X[t * KP + 3] = pack_hl(c4[j * 4 + 0]);
        X[t * KP + 4] = pack_hl(c4[j * 4 + 1]);
        X[t * KP + 5] = pack_hl(c4[j * 4 + 2]);
        X[t * KP + 6] = pack_hl(c4[j * 4 + 3]);
        #pragma unroll
        for (int k = 7; k < 32; ++k) X[t * KP + k] = 0u;
    }
    __syncthreads();

    const unsigned short* wj = wt + j * WJ_STRIDE;
    mfma_layer(X, wj + L0H, wj + L0L, b0 + j * 128, q, lane, 1);
    mfma_layer(X, wj + L1H, wj + L1L, b1 + j * 128, q, lane, 4);
    mfma_layer(X, wj + L2H, wj + L2L, b2 + j * 128, q, lane, 4);

    // --- layer 3: 128 -> 1 (fp32), partials in spare cols 128..131 ---
    {
        const float* w3 = W3 + j * 128 + q * 32;   // wave-uniform
        float part = 0.0f;
        #pragma unroll 8
        for (int kk = 0; kk < 32; ++kk) {
            const unsigned int d = X[lane * KP + q * 32 + kk];
            const float xv = bf2f((unsigned short)(d & 0xffffu))
                           + bf2f((unsigned short)(d >> 16));
            part = fmaf(xv, w3[kk], part);
        }
        X[lane * KP + 128 + q] = __float_as_uint(part);
    }
    __syncthreads();
    if (t < TILE) {
        const int v = v0 + t;
        const float r = b3[j]
            + __uint_as_float(X[t * KP + 128]) + __uint_as_float(X[t * KP + 129])
            + __uint_as_float(X[t * KP + 130]) + __uint_as_float(X[t * KP + 131]);
        if (v < VN) pred[j * VN + v] = r;
    }
}

// ---------------------------------------------------------------------------
// Kernel 4: softmin blend over J
// ---------------------------------------------------------------------------
__global__ __launch_bounds__(256) void softmin_kernel(const float* __restrict__ pred,
                                                      float* __restrict__ out)
{
    const int v = blockIdx.x * 256 + threadIdx.x;
    if (v >= VN) return;
    float vals[JN];
    float m = 3.4e38f;
    #pragma unroll
    for (int jj = 0; jj < JN; ++jj) {
        vals[jj] = pred[jj * VN + v];
        m = fminf(m, vals[jj]);
    }
    float s1 = 0.0f, s2 = 0.0f;
    #pragma unroll
    for (int jj = 0; jj < JN; ++jj) {
        const float d = vals[jj] - m;
        const float e = __expf(-200.0f * d);
        s1 += e;
        s2 = fmaf(d, e, s2);
    }
    out[v] = s2 / s1 + m;
}

extern "C" void kernel_launch(void* const* d_in, const int* in_sizes, int n_in,
                              void* d_out, int out_size, void* d_ws, size_t ws_size,
                              hipStream_t stream)
{
    const float* pts    = (const float*)d_in[0];
    const float* Bcond  = (const float*)d_in[1];
    const float* Btr    = (const float*)d_in[2];
    const float* Brot   = (const float*)d_in[3];
    const float* Bneigh = (const float*)d_in[4];
    const float* ralpha = (const float*)d_in[5];
    const float* rbeta  = (const float*)d_in[6];
    const float* cW0 = (const float*)d_in[7];
    const float* cb0 = (const float*)d_in[8];
    const float* cW1 = (const float*)d_in[9];
    const float* cb1 = (const float*)d_in[10];
    const float* cW2 = (const float*)d_in[11];
    const float* cb2 = (const float*)d_in[12];
    const float* W0 = (const float*)d_in[13];
    const float* b0 = (const float*)d_in[14];
    const float* W1 = (const float*)d_in[15];
    const float* b1 = (const float*)d_in[16];
    const float* W2 = (const float*)d_in[17];
    const float* b2 = (const float*)d_in[18];
    const float* W3 = (const float*)d_in[19];
    const float* b3 = (const float*)d_in[20];

    float* ws   = (float*)d_ws;
    float* pred = ws;                           // JN*VN floats
    float* c4   = ws + JN * VN;                 // 96
    float* geom = c4 + JN * 4;                  // 576
    unsigned short* wt = (unsigned short*)(geom + JN * 2 * 12);  // 24*73728 ushorts

    prep_kernel<<<1, 384, 0, stream>>>(Bcond, Bneigh, ralpha, rbeta,
                                       cW0, cb0, cW1, cb1, cW2, cb2, c4, geom);

    wprep_kernel<<<(JN * 36864) / 256, 256, 0, stream>>>(W0, W1, W2, wt);

    dim3 grid((VN + TILE - 1) / TILE, JN);
    main_kernel<<<grid, 256, 0, stream>>>(pts, Btr, Brot,
                                          b0, b1, b2, W3, b3,
                                          c4, geom, wt, pred);

    softmin_kernel<<<(VN + 255) / 256, 256, 0, stream>>>(pred, (float*)d_out);
}

// Round 7
// 256.295 us; speedup vs baseline: 3.4695x; 1.1872x over previous
//
#include <hip/hip_runtime.h>
#include <hip/hip_bf16.h>
#include <math.h>

#define VN 20000
#define JN 24
#define TILE 64
#define KP 132            // packed-activation row pitch in dwords (round-3 layout)
#define EPSF 1e-8f

typedef __attribute__((ext_vector_type(8))) short bfrag;   // 8 bf16 = 4 VGPRs
typedef __attribute__((ext_vector_type(4))) float f32x4;

// per-joint bf16 weight-plane offsets (ushort units) — round-3 layout
#define WJ_STRIDE 73728
#define L0H 0
#define L0L 4096
#define L1H 8192
#define L1L 24576
#define L2H 40960
#define L2L 57344

__device__ __forceinline__ unsigned short f2bf(float x) {
    __hip_bfloat16 b = __float2bfloat16(x);
    unsigned short u; __builtin_memcpy(&u, &b, 2); return u;
}
__device__ __forceinline__ float bf2f(unsigned short u) {
    __hip_bfloat16 b; __builtin_memcpy(&b, &u, 2);
    return __bfloat162float(b);
}
// packed hi|lo bf16 split via +0x8000 round (cheap, exact residual):
// low ushort = bf16(x) (round-half-up), high ushort = bf16(x - bf16(x))
__device__ __forceinline__ unsigned int pack_hl(float x) {
    const unsigned int ux = __float_as_uint(x) + 0x8000u;
    const unsigned int h  = ux & 0xffff0000u;
    const float lo = x - __uint_as_float(h);
    const unsigned int ul = __float_as_uint(lo) + 0x8000u;
    return (h >> 16) | (ul & 0xffff0000u);
}

// softplus(100x)/100 with ONE transcendental:
// log1p(u), u=e^{-100|x|} in (0,1], deg-5 poly in y=2u-1 (validated round 6)
__device__ __forceinline__ float softplus_fast(float x) {
    const float u = __expf(-100.0f * fabsf(x));
    const float y = 2.0f * u - 1.0f;
    float p = fmaf(y, 0.0009515f, -0.0034665f);
    p = fmaf(y, p, 0.0122786f);
    p = fmaf(y, p, -0.0554079f);
    p = fmaf(y, p, 0.3333420f);
    p = fmaf(y, p, 0.4054545f);
    return fmaf(0.01f, p, fmaxf(x, 0.0f));
}

// ---------------------------------------------------------------------------
// Kernel 1: per-joint prep (VERBATIM round 3, 384 threads)
// geom per (j,gi), 12 floats: g.xyz, h, Jpose.xyz, Jc.xyz, pad, pad
// ---------------------------------------------------------------------------
__global__ __launch_bounds__(384) void prep_kernel(
    const float* __restrict__ Bcond, const float* __restrict__ Bneigh,
    const float* __restrict__ ralpha, const float* __restrict__ rbeta,
    const float* __restrict__ cW0, const float* __restrict__ cb0,
    const float* __restrict__ cW1, const float* __restrict__ cb1,
    const float* __restrict__ cW2, const float* __restrict__ cb2,
    float* __restrict__ c4, float* __restrict__ geom)
{
    __shared__ float hbuf[JN][16];
    const int t = threadIdx.x;

    if (t < JN * 2) {
        const int j = t >> 1, gi = t & 1;
        const float* nb = Bneigh + (j * 2 + gi) * 15;
        const float tx = nb[0],  ty = nb[1],  tz = nb[2];
        const float cx = nb[3],  cy = nb[4],  cz = nb[5];
        const float ox = nb[6],  oy = nb[7],  oz = nb[8];
        const float px = nb[9],  py = nb[10], pz = nb[11];
        const int bid_this  = (int)nb[12];
        const int bid_other = (int)nb[13];
        const float xa_n = ralpha[bid_other * JN + bid_this] - 1.0f;
        const float xa_s = ralpha[bid_this * JN + bid_other] - 1.0f;
        const float a_n = xa_n > 0.0f ? xa_n + 1.0f : expf(xa_n);
        const float a_s = xa_s > 0.0f ? xa_s + 1.0f : expf(xa_s);
        const float be_n = rbeta[bid_other * JN + bid_this];
        const float be_s = rbeta[bid_this * JN + bid_other];

        const float bnx = ox - cx, bny = oy - cy, bnz = oz - cz;
        const float bsx = tx - cx, bsy = ty - cy, bsz = tz - cz;
        const float nb_n = sqrtf(bnx*bnx + bny*bny + bnz*bnz);
        const float nb_s = sqrtf(bsx*bsx + bsy*bsy + bsz*bsz);
        const float f = nb_n / (nb_n + nb_s + EPSF);
        const float vbnx = (ox - tx) * f, vbny = (oy - ty) * f, vbnz = (oz - tz) * f;
        const float g2 = -nb_s / (nb_n + EPSF);
        const float vbsx = vbnx * g2, vbsy = vbny * g2, vbsz = vbnz * g2;
        const float n_n = sqrtf(vbnx*vbnx + vbny*vbny + vbnz*vbnz);
        const float n_s = sqrtf(vbsx*vbsx + vbsy*vbsy + vbsz*vbsz);
        const float trx = ox - vbnx, tr_y = oy - vbny, trz = oz - vbnz;
        const float inn = 1.0f / ((n_n + EPSF) * (n_n + EPSF));
        const float ins = 1.0f / ((n_s + EPSF) * (n_s + EPSF));
        const float gx = vbnx * inn * a_n - vbsx * ins * a_s;
        const float gy = vbny * inn * a_n - vbsy * ins * a_s;
        const float gz = vbnz * inn * a_n - vbsz * ins * a_s;
        const float h = -(trx * gx + tr_y * gy + trz * gz) + be_n - be_s;
        float* gm = geom + (j * 2 + gi) * 12;
        gm[0] = gx; gm[1] = gy; gm[2] = gz; gm[3] = h;
        gm[4] = px; gm[5] = py; gm[6] = pz;
        gm[7] = cx; gm[8] = cy; gm[9] = cz;
        gm[10] = 0.0f; gm[11] = 0.0f;
    }

    {
        const int j = t >> 4, o = t & 15;
        const float* cond = Bcond + j * 288;
        const float* w = cW0 + j * 288 * 16 + o;
        float acc = cb0[j * 16 + o];
        for (int d = 0; d < 288; ++d) acc = fmaf(cond[d], w[d * 16], acc);
        hbuf[j][o] = softplus_fast(acc);
    }
    __syncthreads();
    {
        const int j = t >> 4, o = t & 15;
        const float* w = cW1 + j * 256 + o;
        float acc = cb1[j * 16 + o];
        #pragma unroll
        for (int d = 0; d < 16; ++d) acc = fmaf(hbuf[j][d], w[d * 16], acc);
        acc = softplus_fast(acc);
        __syncthreads();
        hbuf[j][o] = acc;
    }
    __syncthreads();
    if (t < JN * 4) {
        const int j = t >> 2, o = t & 3;
        const float* w = cW2 + j * 64 + o;
        float acc = cb2[j * 4 + o];
        #pragma unroll
        for (int d = 0; d < 16; ++d) acc = fmaf(hbuf[j][d], w[d * 4], acc);
        c4[j * 4 + o] = acc;
    }
}

// ---------------------------------------------------------------------------
// Kernel 2: weight split/transpose into B-fragment order (VERBATIM round 3).
// idx in plane: ((ks*8 + nt)*64 + lane)*8 + j8 maps to W[k][n] with
// n = nt*16 + (lane&15), k = ks*32 + (lane>>4)*8 + j8
// ---------------------------------------------------------------------------
__global__ __launch_bounds__(256) void wprep_kernel(
    const float* __restrict__ W0, const float* __restrict__ W1,
    const float* __restrict__ W2, unsigned short* __restrict__ wt)
{
    const int g = blockIdx.x * 256 + threadIdx.x;   // < 24*36864
    const int jj = g / 36864;
    const int r = g - jj * 36864;
    const float* src; int idx, kin, hoff, loff;
    if (r < 4096)       { idx = r;         kin = 7;   src = W0 + jj * 896;   hoff = L0H; loff = L0L; }
    else if (r < 20480) { idx = r - 4096;  kin = 128; src = W1 + jj * 16384; hoff = L1H; loff = L1L; }
    else                { idx = r - 20480; kin = 128; src = W2 + jj * 16384; hoff = L2H; loff = L2L; }
    const int j8   = idx & 7;
    const int lane = (idx >> 3) & 63;
    const int nt   = (idx >> 9) & 7;
    const int ks   = idx >> 12;
    const int n = nt * 16 + (lane & 15);
    const int k = ks * 32 + (lane >> 4) * 8 + j8;
    const float v = (k < kin) ? src[k * 128 + n] : 0.0f;
    const unsigned short h = f2bf(v);
    const unsigned short l = f2bf(v - bf2f(h));
    unsigned short* dj = wt + jj * WJ_STRIDE;
    dj[hoff + idx] = h;
    dj[loff + idx] = l;
}

// ---------------------------------------------------------------------------
// Kernel 3: main (round-3 layout EXACTLY: single packed hi|lo dword plane,
// pitch KP=132 dwords, full-dword LDS writes only).
// Arithmetic-only changes vs round 3: bias in acc init, v_perm unpack,
// poly softplus, cheap pack_hl.
// ---------------------------------------------------------------------------
__device__ __forceinline__ void mfma_layer(
    unsigned int* __restrict__ X,
    const unsigned short* __restrict__ wh,
    const unsigned short* __restrict__ wl,
    const float* __restrict__ bvec,
    int q, int lane, int nks)
{
    const int l = lane & 15;
    const int quad = lane >> 4;
    const float bia0 = bvec[q * 32 + l];        // ni=0 channel bias (col l)
    const float bia1 = bvec[q * 32 + 16 + l];   // ni=1
    f32x4 acc[4][2];
    #pragma unroll
    for (int mi = 0; mi < 4; ++mi) {
        acc[mi][0] = (f32x4){bia0, bia0, bia0, bia0};
        acc[mi][1] = (f32x4){bia1, bia1, bia1, bia1};
    }

    #pragma unroll 1
    for (int ks = 0; ks < nks; ++ks) {
        bfrag bh[2], bl[2];
        #pragma unroll
        for (int ni = 0; ni < 2; ++ni) {
            const int off = ((ks * 8 + (q * 2 + ni)) * 64 + lane) * 8;
            bh[ni] = *(const bfrag*)(wh + off);   // coalesced 16B/lane
            bl[ni] = *(const bfrag*)(wl + off);
        }
        #pragma unroll
        for (int mi = 0; mi < 4; ++mi) {
            const unsigned int* ap = X + (mi * 16 + l) * KP + ks * 32 + quad * 8;
            union { uint4 v[2]; unsigned int u[8]; } d;
            d.v[0] = *(const uint4*)ap;           // ds_read_b128 x2
            d.v[1] = *(const uint4*)(ap + 4);
            union { unsigned int u[4]; bfrag f; } ah, al;
            #pragma unroll
            for (int jj = 0; jj < 4; ++jj) {
                // lo halves (hi-plane bf16) and hi halves (lo-plane bf16)
                ah.u[jj] = __builtin_amdgcn_perm(d.u[2*jj+1], d.u[2*jj], 0x05040100u);
                al.u[jj] = __builtin_amdgcn_perm(d.u[2*jj+1], d.u[2*jj], 0x07060302u);
            }
            #pragma unroll
            for (int ni = 0; ni < 2; ++ni) {
                acc[mi][ni] = __builtin_amdgcn_mfma_f32_16x16x32_bf16(ah.f, bh[ni], acc[mi][ni], 0, 0, 0);
                acc[mi][ni] = __builtin_amdgcn_mfma_f32_16x16x32_bf16(al.f, bh[ni], acc[mi][ni], 0, 0, 0);
                acc[mi][ni] = __builtin_amdgcn_mfma_f32_16x16x32_bf16(ah.f, bl[ni], acc[mi][ni], 0, 0, 0);
            }
        }
    }
    __syncthreads();   // all A reads done before overwrite
    #pragma unroll
    for (int ni = 0; ni < 2; ++ni) {
        const int ch = q * 32 + ni * 16 + l;
        #pragma unroll
        for (int mi = 0; mi < 4; ++mi) {
            #pragma unroll
            for (int r = 0; r < 4; ++r) {
                const float v = softplus_fast(acc[mi][ni][r]);
                const int p = mi * 16 + quad * 4 + r;
                X[p * KP + ch] = pack_hl(v);
            }
        }
    }
    __syncthreads();
}

__global__ __launch_bounds__(256, 4) void main_kernel(
    const float* __restrict__ pts, const float* __restrict__ Btr,
    const float* __restrict__ Brot,
    const float* __restrict__ b0, const float* __restrict__ b1,
    const float* __restrict__ b2, const float* __restrict__ W3,
    const float* __restrict__ b3,
    const float* __restrict__ c4, const float* __restrict__ geom,
    const unsigned short* __restrict__ wt,
    float* __restrict__ pred)
{
    __shared__ unsigned int X[TILE * KP];
    const int j = blockIdx.y;
    const int v0 = blockIdx.x * TILE;
    const int t = threadIdx.x;
    const int lane = t & 63;
    const int q = __builtin_amdgcn_readfirstlane(t >> 6);

    // --- phase 0: local coords + neighbor deformation -> packed input rows ---
    if (t < TILE) {
        const int v = v0 + t;
        float plx = 0.0f, ply = 0.0f, plz = 0.0f;
        if (v < VN) {
            const float dx = pts[v * 3 + 0] - Btr[j * 3 + 0];
            const float dy = pts[v * 3 + 1] - Btr[j * 3 + 1];
            const float dz = pts[v * 3 + 2] - Btr[j * 3 + 2];
            const float* R = Brot + j * 9;
            plx = R[0] * dx + R[3] * dy + R[6] * dz;
            ply = R[1] * dx + R[4] * dy + R[7] * dz;
            plz = R[2] * dx + R[5] * dy + R[8] * dz;
            float osx = 0.0f, osy = 0.0f, osz = 0.0f;
            #pragma unroll
            for (int gi = 0; gi < 2; ++gi) {
                const float* gm = geom + (j * 2 + gi) * 12;
                const float arg = plx * gm[0] + ply * gm[1] + plz * gm[2] + gm[3];
                const float w = 1.0f / (1.0f + __expf(-arg));
                const float aax = -gm[4] * w, aay = -gm[5] * w, aaz = -gm[6] * w;
                const float jcx = gm[7], jcy = gm[8], jcz = gm[9];
                const float ang = sqrtf(aax * aax + aay * aay + aaz * aaz);
                const float inv = ang < 1e-12f ? 1.0f : 1.0f / ang;
                const float ux = aax * inv, uy = aay * inv, uz = aaz * inv;
                const float co = __cosf(ang), si = __sinf(ang), C = 1.0f - co;
                const float vx = plx - jcx, vy = ply - jcy, vz = plz - jcz;
                const float du = ux * vx + uy * vy + uz * vz;
                const float cxv = uy * vz - uz * vy;
                const float cyv = uz * vx - ux * vz;
                const float czv = ux * vy - uy * vx;
                float offx = co * vx + si * cxv + C * ux * du + jcx - plx;
                float offy = co * vy + si * cyv + C * uy * du + jcy - ply;
                float offz = co * vz + si * czv + C * uz * du + jcz - plz;
                if (isnan(offx)) offx = 0.0f;
                if (isnan(offy)) offy = 0.0f;
                if (isnan(offz)) offz = 0.0f;
                osx += offx; osy += offy; osz += offz;
            }
            plx += osx; ply += osy; plz += osz;
        }
        X[t * KP + 0] = pack_hl(plx);
        X[t * KP + 1] = pack_hl(ply);
        X[t * KP + 2] = pack_hl(plz);
        X[t * KP + 3] = pack_hl(c4[j * 4 + 0]);
        X[t * KP + 4] = pack_hl(c4[j * 4 + 1]);
        X[t * KP + 5] = pack_hl(c4[j * 4 + 2]);
        X[t * KP + 6] = pack_hl(c4[j * 4 + 3]);
        #pragma unroll
        for (int k = 7; k < 32; ++k) X[t * KP + k] = 0u;
    }
    __syncthreads();

    const unsigned short* wj = wt + j * WJ_STRIDE;
    mfma_layer(X, wj + L0H, wj + L0L, b0 + j * 128, q, lane, 1);
    mfma_layer(X, wj + L1H, wj + L1L, b1 + j * 128, q, lane, 4);
    mfma_layer(X, wj + L2H, wj + L2L, b2 + j * 128, q, lane, 4);

    // --- layer 3: 128 -> 1 (fp32), partials in spare cols 128..131 ---
    {
        const float* w3 = W3 + j * 128 + q * 32;   // wave-uniform
        float part = 0.0f;
        #pragma unroll 8
        for (int kk = 0; kk < 32; ++kk) {
            const unsigned int d = X[lane * KP + q * 32 + kk];
            const float xv = __uint_as_float(d << 16)
                           + __uint_as_float(d & 0xffff0000u);
            part = fmaf(xv, w3[kk], part);
        }
        X[lane * KP + 128 + q] = __float_as_uint(part);
    }
    __syncthreads();
    if (t < TILE) {
        const int v = v0 + t;
        const float r = b3[j]
            + __uint_as_float(X[t * KP + 128]) + __uint_as_float(X[t * KP + 129])
            + __uint_as_float(X[t * KP + 130]) + __uint_as_float(X[t * KP + 131]);
        if (v < VN) pred[j * VN + v] = r;
    }
}

// ---------------------------------------------------------------------------
// Kernel 4: softmin blend over J
// ---------------------------------------------------------------------------
__global__ __launch_bounds__(256) void softmin_kernel(const float* __restrict__ pred,
                                                      float* __restrict__ out)
{
    const int v = blockIdx.x * 256 + threadIdx.x;
    if (v >= VN) return;
    float vals[JN];
    float m = 3.4e38f;
    #pragma unroll
    for (int jj = 0; jj < JN; ++jj) {
        vals[jj] = pred[jj * VN + v];
        m = fminf(m, vals[jj]);
    }
    float s1 = 0.0f, s2 = 0.0f;
    #pragma unroll
    for (int jj = 0; jj < JN; ++jj) {
        const float d = vals[jj] - m;
        const float e = __expf(-200.0f * d);
        s1 += e;
        s2 = fmaf(d, e, s2);
    }
    out[v] = s2 / s1 + m;
}

extern "C" void kernel_launch(void* const* d_in, const int* in_sizes, int n_in,
                              void* d_out, int out_size, void* d_ws, size_t ws_size,
                              hipStream_t stream)
{
    const float* pts    = (const float*)d_in[0];
    const float* Bcond  = (const float*)d_in[1];
    const float* Btr    = (const float*)d_in[2];
    const float* Brot   = (const float*)d_in[3];
    const float* Bneigh = (const float*)d_in[4];
    const float* ralpha = (const float*)d_in[5];
    const float* rbeta  = (const float*)d_in[6];
    const float* cW0 = (const float*)d_in[7];
    const float* cb0 = (const float*)d_in[8];
    const float* cW1 = (const float*)d_in[9];
    const float* cb1 = (const float*)d_in[10];
    const float* cW2 = (const float*)d_in[11];
    const float* cb2 = (const float*)d_in[12];
    const float* W0 = (const float*)d_in[13];
    const float* b0 = (const float*)d_in[14];
    const float* W1 = (const float*)d_in[15];
    const float* b1 = (const float*)d_in[16];
    const float* W2 = (const float*)d_in[17];
    const float* b2 = (const float*)d_in[18];
    const float* W3 = (const float*)d_in[19];
    const float* b3 = (const float*)d_in[20];

    float* ws   = (float*)d_ws;
    float* pred = ws;                           // JN*VN floats
    float* c4   = ws + JN * VN;                 // 96
    float* geom = c4 + JN * 4;                  // 576
    unsigned short* wt = (unsigned short*)(geom + JN * 2 * 12);  // 24*73728 ushorts

    prep_kernel<<<1, 384, 0, stream>>>(Bcond, Bneigh, ralpha, rbeta,
                                       cW0, cb0, cW1, cb1, cW2, cb2, c4, geom);

    wprep_kernel<<<(JN * 36864) / 256, 256, 0, stream>>>(W0, W1, W2, wt);

    dim3 grid((VN + TILE - 1) / TILE, JN);
    main_kernel<<<grid, 256, 0, stream>>>(pts, Btr, Brot,
                                          b0, b1, b2, W3, b3,
                                          c4, geom, wt, pred);

    softmin_kernel<<<(VN + 255) / 256, 256, 0, stream>>>(pred, (float*)d_out);
}

// Round 10
// 256.052 us; speedup vs baseline: 3.4728x; 1.0009x over previous
//
#include <hip/hip_runtime.h>
#include <hip/hip_bf16.h>
#include <math.h>

#define VN 20000
#define JN 24
#define TILE 64
#define KP 132            // packed-activation row pitch in dwords (round-3 layout)
#define EPSF 1e-8f

typedef __attribute__((ext_vector_type(8))) short bfrag;   // 8 bf16 = 4 VGPRs
typedef __attribute__((ext_vector_type(4))) float f32x4;

// per-joint bf16 weight-plane offsets (ushort units) — round-3 layout
#define WJ_STRIDE 73728
#define L0H 0
#define L0L 4096
#define L1H 8192
#define L1L 24576
#define L2H 40960
#define L2L 57344

__device__ __forceinline__ unsigned short f2bf(float x) {
    __hip_bfloat16 b = __float2bfloat16(x);
    unsigned short u; __builtin_memcpy(&u, &b, 2); return u;
}
__device__ __forceinline__ float bf2f(unsigned short u) {
    __hip_bfloat16 b; __builtin_memcpy(&b, &u, 2);
    return __bfloat162float(b);
}
// packed hi|lo bf16 split via +0x8000 round (cheap, exact residual):
// low ushort = bf16(x) (round-half-up), high ushort = bf16(x - bf16(x))
__device__ __forceinline__ unsigned int pack_hl(float x) {
    const unsigned int ux = __float_as_uint(x) + 0x8000u;
    const unsigned int h  = ux & 0xffff0000u;
    const float lo = x - __uint_as_float(h);
    const unsigned int ul = __float_as_uint(lo) + 0x8000u;
    return (h >> 16) | (ul & 0xffff0000u);
}

// softplus(100x)/100 with ONE transcendental:
// log1p(u), u=e^{-100|x|} in (0,1], deg-5 poly in y=2u-1 (validated r6/r7)
__device__ __forceinline__ float softplus_fast(float x) {
    const float u = __expf(-100.0f * fabsf(x));
    const float y = 2.0f * u - 1.0f;
    float p = fmaf(y, 0.0009515f, -0.0034665f);
    p = fmaf(y, p, 0.0122786f);
    p = fmaf(y, p, -0.0554079f);
    p = fmaf(y, p, 0.3333420f);
    p = fmaf(y, p, 0.4054545f);
    return fmaf(0.01f, p, fmaxf(x, 0.0f));
}

// ---------------------------------------------------------------------------
// Kernel 1: per-joint prep (VERBATIM round 3/7, 384 threads)
// geom per (j,gi), 12 floats: g.xyz, h, Jpose.xyz, Jc.xyz, pad, pad
// ---------------------------------------------------------------------------
__global__ __launch_bounds__(384) void prep_kernel(
    const float* __restrict__ Bcond, const float* __restrict__ Bneigh,
    const float* __restrict__ ralpha, const float* __restrict__ rbeta,
    const float* __restrict__ cW0, const float* __restrict__ cb0,
    const float* __restrict__ cW1, const float* __restrict__ cb1,
    const float* __restrict__ cW2, const float* __restrict__ cb2,
    float* __restrict__ c4, float* __restrict__ geom)
{
    __shared__ float hbuf[JN][16];
    const int t = threadIdx.x;

    if (t < JN * 2) {
        const int j = t >> 1, gi = t & 1;
        const float* nb = Bneigh + (j * 2 + gi) * 15;
        const float tx = nb[0],  ty = nb[1],  tz = nb[2];
        const float cx = nb[3],  cy = nb[4],  cz = nb[5];
        const float ox = nb[6],  oy = nb[7],  oz = nb[8];
        const float px = nb[9],  py = nb[10], pz = nb[11];
        const int bid_this  = (int)nb[12];
        const int bid_other = (int)nb[13];
        const float xa_n = ralpha[bid_other * JN + bid_this] - 1.0f;
        const float xa_s = ralpha[bid_this * JN + bid_other] - 1.0f;
        const float a_n = xa_n > 0.0f ? xa_n + 1.0f : expf(xa_n);
        const float a_s = xa_s > 0.0f ? xa_s + 1.0f : expf(xa_s);
        const float be_n = rbeta[bid_other * JN + bid_this];
        const float be_s = rbeta[bid_this * JN + bid_other];

        const float bnx = ox - cx, bny = oy - cy, bnz = oz - cz;
        const float bsx = tx - cx, bsy = ty - cy, bsz = tz - cz;
        const float nb_n = sqrtf(bnx*bnx + bny*bny + bnz*bnz);
        const float nb_s = sqrtf(bsx*bsx + bsy*bsy + bsz*bsz);
        const float f = nb_n / (nb_n + nb_s + EPSF);
        const float vbnx = (ox - tx) * f, vbny = (oy - ty) * f, vbnz = (oz - tz) * f;
        const float g2 = -nb_s / (nb_n + EPSF);
        const float vbsx = vbnx * g2, vbsy = vbny * g2, vbsz = vbnz * g2;
        const float n_n = sqrtf(vbnx*vbnx + vbny*vbny + vbnz*vbnz);
        const float n_s = sqrtf(vbsx*vbsx + vbsy*vbsy + vbsz*vbsz);
        const float trx = ox - vbnx, tr_y = oy - vbny, trz = oz - vbnz;
        const float inn = 1.0f / ((n_n + EPSF) * (n_n + EPSF));
        const float ins = 1.0f / ((n_s + EPSF) * (n_s + EPSF));
        const float gx = vbnx * inn * a_n - vbsx * ins * a_s;
        const float gy = vbny * inn * a_n - vbsy * ins * a_s;
        const float gz = vbnz * inn * a_n - vbsz * ins * a_s;
        const float h = -(trx * gx + tr_y * gy + trz * gz) + be_n - be_s;
        float* gm = geom + (j * 2 + gi) * 12;
        gm[0] = gx; gm[1] = gy; gm[2] = gz; gm[3] = h;
        gm[4] = px; gm[5] = py; gm[6] = pz;
        gm[7] = cx; gm[8] = cy; gm[9] = cz;
        gm[10] = 0.0f; gm[11] = 0.0f;
    }

    {
        const int j = t >> 4, o = t & 15;
        const float* cond = Bcond + j * 288;
        const float* w = cW0 + j * 288 * 16 + o;
        float acc = cb0[j * 16 + o];
        for (int d = 0; d < 288; ++d) acc = fmaf(cond[d], w[d * 16], acc);
        hbuf[j][o] = softplus_fast(acc);
    }
    __syncthreads();
    {
        const int j = t >> 4, o = t & 15;
        const float* w = cW1 + j * 256 + o;
        float acc = cb1[j * 16 + o];
        #pragma unroll
        for (int d = 0; d < 16; ++d) acc = fmaf(hbuf[j][d], w[d * 16], acc);
        acc = softplus_fast(acc);
        __syncthreads();
        hbuf[j][o] = acc;
    }
    __syncthreads();
    if (t < JN * 4) {
        const int j = t >> 2, o = t & 3;
        const float* w = cW2 + j * 64 + o;
        float acc = cb2[j * 4 + o];
        #pragma unroll
        for (int d = 0; d < 16; ++d) acc = fmaf(hbuf[j][d], w[d * 4], acc);
        c4[j * 4 + o] = acc;
    }
}

// ---------------------------------------------------------------------------
// Kernel 2: weight split/transpose into B-fragment order (VERBATIM round 3).
// idx in plane: ((ks*8 + nt)*64 + lane)*8 + j8 maps to W[k][n] with
// n = nt*16 + (lane&15), k = ks*32 + (lane>>4)*8 + j8
// ---------------------------------------------------------------------------
__global__ __launch_bounds__(256) void wprep_kernel(
    const float* __restrict__ W0, const float* __restrict__ W1,
    const float* __restrict__ W2, unsigned short* __restrict__ wt)
{
    const int g = blockIdx.x * 256 + threadIdx.x;   // < 24*36864
    const int jj = g / 36864;
    const int r = g - jj * 36864;
    const float* src; int idx, kin, hoff, loff;
    if (r < 4096)       { idx = r;         kin = 7;   src = W0 + jj * 896;   hoff = L0H; loff = L0L; }
    else if (r < 20480) { idx = r - 4096;  kin = 128; src = W1 + jj * 16384; hoff = L1H; loff = L1L; }
    else                { idx = r - 20480; kin = 128; src = W2 + jj * 16384; hoff = L2H; loff = L2L; }
    const int j8   = idx & 7;
    const int lane = (idx >> 3) & 63;
    const int nt   = (idx >> 9) & 7;
    const int ks   = idx >> 12;
    const int n = nt * 16 + (lane & 15);
    const int k = ks * 32 + (lane >> 4) * 8 + j8;
    const float v = (k < kin) ? src[k * 128 + n] : 0.0f;
    const unsigned short h = f2bf(v);
    const unsigned short l = f2bf(v - bf2f(h));
    unsigned short* dj = wt + jj * WJ_STRIDE;
    dj[hoff + idx] = h;
    dj[loff + idx] = l;
}

// ---------------------------------------------------------------------------
// Kernel 3: main (round-7 verified source: single packed hi|lo dword plane,
// pitch KP=132 dwords, full-dword LDS writes only; bias in acc init,
// v_perm unpack, deg-5 poly softplus, cheap pack_hl, ks loop unroll 1).
// ---------------------------------------------------------------------------
__device__ __forceinline__ void mfma_layer(
    unsigned int* __restrict__ X,
    const unsigned short* __restrict__ wh,
    const unsigned short* __restrict__ wl,
    const float* __restrict__ bvec,
    int q, int lane, int nks)
{
    const int l = lane & 15;
    const int quad = lane >> 4;
    const float bia0 = bvec[q * 32 + l];        // ni=0 channel bias (col l)
    const float bia1 = bvec[q * 32 + 16 + l];   // ni=1
    f32x4 acc[4][2];
    #pragma unroll
    for (int mi = 0; mi < 4; ++mi) {
        acc[mi][0] = (f32x4){bia0, bia0, bia0, bia0};
        acc[mi][1] = (f32x4){bia1, bia1, bia1, bia1};
    }

    #pragma unroll 1
    for (int ks = 0; ks < nks; ++ks) {
        bfrag bh[2], bl[2];
        #pragma unroll
        for (int ni = 0; ni < 2; ++ni) {
            const int off = ((ks * 8 + (q * 2 + ni)) * 64 + lane) * 8;
            bh[ni] = *(const bfrag*)(wh + off);   // coalesced 16B/lane
            bl[ni] = *(const bfrag*)(wl + off);
        }
        #pragma unroll
        for (int mi = 0; mi < 4; ++mi) {
            const unsigned int* ap = X + (mi * 16 + l) * KP + ks * 32 + quad * 8;
            union { uint4 v[2]; unsigned int u[8]; } d;
            d.v[0] = *(const uint4*)ap;           // ds_read_b128 x2
            d.v[1] = *(const uint4*)(ap + 4);
            union { unsigned int u[4]; bfrag f; } ah, al;
            #pragma unroll
            for (int jj = 0; jj < 4; ++jj) {
                // lo halves (hi-plane bf16) and hi halves (lo-plane bf16)
                ah.u[jj] = __builtin_amdgcn_perm(d.u[2*jj+1], d.u[2*jj], 0x05040100u);
                al.u[jj] = __builtin_amdgcn_perm(d.u[2*jj+1], d.u[2*jj], 0x07060302u);
            }
            #pragma unroll
            for (int ni = 0; ni < 2; ++ni) {
                acc[mi][ni] = __builtin_amdgcn_mfma_f32_16x16x32_bf16(ah.f, bh[ni], acc[mi][ni], 0, 0, 0);
                acc[mi][ni] = __builtin_amdgcn_mfma_f32_16x16x32_bf16(al.f, bh[ni], acc[mi][ni], 0, 0, 0);
                acc[mi][ni] = __builtin_amdgcn_mfma_f32_16x16x32_bf16(ah.f, bl[ni], acc[mi][ni], 0, 0, 0);
            }
        }
    }
    __syncthreads();   // all A reads done before overwrite
    #pragma unroll
    for (int ni = 0; ni < 2; ++ni) {
        const int ch = q * 32 + ni * 16 + l;
        #pragma unroll
        for (int mi = 0; mi < 4; ++mi) {
            #pragma unroll
            for (int r = 0; r < 4; ++r) {
                const float v = softplus_fast(acc[mi][ni][r]);
                const int p = mi * 16 + quad * 4 + r;
                X[p * KP + ch] = pack_hl(v);
            }
        }
    }
    __syncthreads();
}

__global__ __launch_bounds__(256, 4) void main_kernel(
    const float* __restrict__ pts, const float* __restrict__ Btr,
    const float* __restrict__ Brot,
    const float* __restrict__ b0, const float* __restrict__ b1,
    const float* __restrict__ b2, const float* __restrict__ W3,
    const float* __restrict__ b3,
    const float* __restrict__ c4, const float* __restrict__ geom,
    const unsigned short* __restrict__ wt,
    float* __restrict__ pred)
{
    __shared__ unsigned int X[TILE * KP];
    const int j = blockIdx.y;
    const int v0 = blockIdx.x * TILE;
    const int t = threadIdx.x;
    const int lane = t & 63;
    const int q = __builtin_amdgcn_readfirstlane(t >> 6);

    // --- phase 0: local coords + neighbor deformation -> packed input rows ---
    if (t < TILE) {
        const int v = v0 + t;
        float plx = 0.0f, ply = 0.0f, plz = 0.0f;
        if (v < VN) {
            const float dx = pts[v * 3 + 0] - Btr[j * 3 + 0];
            const float dy = pts[v * 3 + 1] - Btr[j * 3 + 1];
            const float dz = pts[v * 3 + 2] - Btr[j * 3 + 2];
            const float* R = Brot + j * 9;
            plx = R[0] * dx + R[3] * dy + R[6] * dz;
            ply = R[1] * dx + R[4] * dy + R[7] * dz;
            plz = R[2] * dx + R[5] * dy + R[8] * dz;
            float osx = 0.0f, osy = 0.0f, osz = 0.0f;
            #pragma unroll
            for (int gi = 0; gi < 2; ++gi) {
                const float* gm = geom + (j * 2 + gi) * 12;
                const float arg = plx * gm[0] + ply * gm[1] + plz * gm[2] + gm[3];
                const float w = 1.0f / (1.0f + __expf(-arg));
                const float aax = -gm[4] * w, aay = -gm[5] * w, aaz = -gm[6] * w;
                const float jcx = gm[7], jcy = gm[8], jcz = gm[9];
                const float ang = sqrtf(aax * aax + aay * aay + aaz * aaz);
                const float inv = ang < 1e-12f ? 1.0f : 1.0f / ang;
                const float ux = aax * inv, uy = aay * inv, uz = aaz * inv;
                const float co = __cosf(ang), si = __sinf(ang), C = 1.0f - co;
                const float vx = plx - jcx, vy = ply - jcy, vz = plz - jcz;
                const float du = ux * vx + uy * vy + uz * vz;
                const float cxv = uy * vz - uz * vy;
                const float cyv = uz * vx - ux * vz;
                const float czv = ux * vy - uy * vx;
                float offx = co * vx + si * cxv + C * ux * du + jcx - plx;
                float offy = co * vy + si * cyv + C * uy * du + jcy - ply;
                float offz = co * vz + si * czv + C * uz * du + jcz - plz;
                if (isnan(offx)) offx = 0.0f;
                if (isnan(offy)) offy = 0.0f;
                if (isnan(offz)) offz = 0.0f;
                osx += offx; osy += offy; osz += offz;
            }
            plx += osx; ply += osy; plz += osz;
        }
        X[t * KP + 0] = pack_hl(plx);
        X[t * KP + 1] = pack_hl(ply);
        X[t * KP + 2] = pack_hl(plz);
        X[t * KP + 3] = pack_hl(c4[j * 4 + 0]);
        X[t * KP + 4] = pack_hl(c4[j * 4 + 1]);
        X[t * KP + 5] = pack_hl(c4[j * 4 + 2]);
        X[t * KP + 6] = pack_hl(c4[j * 4 + 3]);
        #pragma unroll
        for (int k = 7; k < 32; ++k) X[t * KP + k] = 0u;
    }
    __syncthreads();

    const unsigned short* wj = wt + j * WJ_STRIDE;
    mfma_layer(X, wj + L0H, wj + L0L, b0 + j * 128, q, lane, 1);
    mfma_layer(X, wj + L1H, wj + L1L, b1 + j * 128, q, lane, 4);
    mfma_layer(X, wj + L2H, wj + L2L, b2 + j * 128, q, lane, 4);

    // --- layer 3: 128 -> 1 (fp32), partials in spare cols 128..131 ---
    {
        const float* w3 = W3 + j * 128 + q * 32;   // wave-uniform
        float part = 0.0f;
        #pragma unroll 8
        for (int kk = 0; kk < 32; ++kk) {
            const unsigned int d = X[lane * KP + q * 32 + kk];
            const float xv = __uint_as_float(d << 16)
                           + __uint_as_float(d & 0xffff0000u);
            part = fmaf(xv, w3[kk], part);
        }
        X[lane * KP + 128 + q] = __float_as_uint(part);
    }
    __syncthreads();
    if (t < TILE) {
        const int v = v0 + t;
        const float r = b3[j]
            + __uint_as_float(X[t * KP + 128]) + __uint_as_float(X[t * KP + 129])
            + __uint_as_float(X[t * KP + 130]) + __uint_as_float(X[t * KP + 131]);
        if (v < VN) pred[j * VN + v] = r;
    }
}

// ---------------------------------------------------------------------------
// Kernel 4: softmin blend over J
// ---------------------------------------------------------------------------
__global__ __launch_bounds__(256) void softmin_kernel(const float* __restrict__ pred,
                                                      float* __restrict__ out)
{
    const int v = blockIdx.x * 256 + threadIdx.x;
    if (v >= VN) return;
    float vals[JN];
    float m = 3.4e38f;
    #pragma unroll
    for (int jj = 0; jj < JN; ++jj) {
        vals[jj] = pred[jj * VN + v];
        m = fminf(m, vals[jj]);
    }
    float s1 = 0.0f, s2 = 0.0f;
    #pragma unroll
    for (int jj = 0; jj < JN; ++jj) {
        const float d = vals[jj] - m;
        const float e = __expf(-200.0f * d);
        s1 += e;
        s2 = fmaf(d, e, s2);
    }
    out[v] = s2 / s1 + m;
}

extern "C" void kernel_launch(void* const* d_in, const int* in_sizes, int n_in,
                              void* d_out, int out_size, void* d_ws, size_t ws_size,
                              hipStream_t stream)
{
    const float* pts    = (const float*)d_in[0];
    const float* Bcond  = (const float*)d_in[1];
    const float* Btr    = (const float*)d_in[2];
    const float* Brot   = (const float*)d_in[3];
    const float* Bneigh = (const float*)d_in[4];
    const float* ralpha = (const float*)d_in[5];
    const float* rbeta  = (const float*)d_in[6];
    const float* cW0 = (const float*)d_in[7];
    const float* cb0 = (const float*)d_in[8];
    const float* cW1 = (const float*)d_in[9];
    const float* cb1 = (const float*)d_in[10];
    const float* cW2 = (const float*)d_in[11];
    const float* cb2 = (const float*)d_in[12];
    const float* W0 = (const float*)d_in[13];
    const float* b0 = (const float*)d_in[14];
    const float* W1 = (const float*)d_in[15];
    const float* b1 = (const float*)d_in[16];
    const float* W2 = (const float*)d_in[17];
    const float* b2 = (const float*)d_in[18];
    const float* W3 = (const float*)d_in[19];
    const float* b3 = (const float*)d_in[20];

    float* ws   = (float*)d_ws;
    float* pred = ws;                           // JN*VN floats
    float* c4   = ws + JN * VN;                 // 96
    float* geom = c4 + JN * 4;                  // 576
    unsigned short* wt = (unsigned short*)(geom + JN * 2 * 12);  // 24*73728 ushorts

    prep_kernel<<<1, 384, 0, stream>>>(Bcond, Bneigh, ralpha, rbeta,
                                       cW0, cb0, cW1, cb1, cW2, cb2, c4, geom);

    wprep_kernel<<<(JN * 36864) / 256, 256, 0, stream>>>(W0, W1, W2, wt);

    dim3 grid((VN + TILE - 1) / TILE, JN);
    main_kernel<<<grid, 256, 0, stream>>>(pts, Btr, Brot,
                                          b0, b1, b2, W3, b3,
                                          c4, geom, wt, pred);

    softmin_kernel<<<(VN + 255) / 256, 256, 0, stream>>>(pred, (float*)d_out);
}